// Round 1
// baseline (888.885 us; speedup 1.0000x reference)
//
#include <hip/hip_runtime.h>

// EFDM loss — reduced form:
//   pos_sum[b]  = sum over (a,p,c,j) of (sortT[a,p,b,c][j] - sortS[a,p,b,c][j])^2
//   neg_sum[b]  = sum over (a,p,k,c,j) of (sortT[a,p,b,c][j] - sortS[a,p,nb(b,k),c][j])^2
//   out = sum_b pos_sum[b]/neg_sum[b]          (the 1/(C*N) mean factors cancel)
//
// L=2, P=2, B=4, C=128, N=H*W=4096, K=2.  Rows = 2L*P*B*C = 4096.
// Concat along axis 0 means S rows [0,2048) come flat from style_E,
// rows [2048,4096) from style_S (same for T / translate).

constexpr int N     = 4096;   // H*W
constexpr int NTH   = 256;
constexpr int CDIM  = 128;
constexpr int BDIM  = 4;
constexpr int KNEG  = 2;
constexpr int ROWS  = 4096;   // 2L*P*B*C
constexpr int HALF  = 2048;   // rows per source tensor

// In-LDS bitonic sort of N floats, ascending. Caller must __syncthreads()
// after filling buf. Leaves buf synchronized (last pass ends with barrier).
__device__ inline void bitonic_sort(float* buf) {
  const int tid = threadIdx.x;
  for (int k = 2; k <= N; k <<= 1) {
    for (int j = k >> 1; j > 0; j >>= 1) {
      #pragma unroll 1
      for (int i = tid; i < N; i += NTH) {
        const int l = i ^ j;
        if (l > i) {
          const float a = buf[i];
          const float b = buf[l];
          const bool up = ((i & k) == 0);
          if ((a > b) == up) { buf[i] = b; buf[l] = a; }
        }
      }
      __syncthreads();
    }
  }
}

__global__ __launch_bounds__(NTH)
void sort_rows(const float* __restrict__ a0, const float* __restrict__ a1,
               float* __restrict__ out) {
  __shared__ float buf[N];
  const int r = blockIdx.x;
  const float* src = (r < HALF) ? a0 + (size_t)r * N
                                : a1 + (size_t)(r - HALF) * N;
  for (int j = threadIdx.x; j < N; j += NTH) buf[j] = src[j];
  __syncthreads();
  bitonic_sort(buf);
  float* dst = out + (size_t)r * N;
  for (int j = threadIdx.x; j < N; j += NTH) dst[j] = buf[j];
}

__global__ __launch_bounds__(NTH)
void loss_rows(const float* __restrict__ t0, const float* __restrict__ t1,
               const float* __restrict__ Vs, const int* __restrict__ neg_idx,
               double* __restrict__ acc) {
  __shared__ float buf[N];
  __shared__ float red[2][4];
  const int tid = threadIdx.x;
  const int r = blockIdx.x;
  const float* src = (r < HALF) ? t0 + (size_t)r * N
                                : t1 + (size_t)(r - HALF) * N;
  for (int j = tid; j < N; j += NTH) buf[j] = src[j];
  __syncthreads();
  bitonic_sort(buf);

  // r = ((ap)*B + b)*C + c,  ap in [0,8)
  const int c  = r & (CDIM - 1);
  const int b  = (r / CDIM) & (BDIM - 1);
  const int ap = r / (CDIM * BDIM);

  float posp = 0.f, negp = 0.f;
  const float* vp = Vs + (size_t)r * N;
  for (int j = tid; j < N; j += NTH) {
    const float d = buf[j] - vp[j];
    posp += d * d;
  }
  #pragma unroll
  for (int k = 0; k < KNEG; ++k) {
    const int nb = neg_idx[b * KNEG + k];
    const float* vn = Vs + ((size_t)(ap * BDIM + nb) * CDIM + c) * N;
    for (int j = tid; j < N; j += NTH) {
      const float d = buf[j] - vn[j];
      negp += d * d;
    }
  }

  // wave64 shuffle reduce, then cross-wave via LDS
  for (int off = 32; off > 0; off >>= 1) {
    posp += __shfl_down(posp, off, 64);
    negp += __shfl_down(negp, off, 64);
  }
  const int wid = tid >> 6, lane = tid & 63;
  if (lane == 0) { red[0][wid] = posp; red[1][wid] = negp; }
  __syncthreads();
  if (tid == 0) {
    const float pt = red[0][0] + red[0][1] + red[0][2] + red[0][3];
    const float nt = red[1][0] + red[1][1] + red[1][2] + red[1][3];
    atomicAdd(&acc[b], (double)pt);
    atomicAdd(&acc[BDIM + b], (double)nt);
  }
}

__global__ void finalize(const double* __restrict__ acc, float* __restrict__ out) {
  if (threadIdx.x == 0 && blockIdx.x == 0) {
    double s = 0.0;
    for (int b = 0; b < BDIM; ++b) s += acc[b] / acc[BDIM + b];
    out[0] = (float)s;
  }
}

extern "C" void kernel_launch(void* const* d_in, const int* in_sizes, int n_in,
                              void* d_out, int out_size, void* d_ws, size_t ws_size,
                              hipStream_t stream) {
  const float* style_E = (const float*)d_in[0];
  const float* style_S = (const float*)d_in[1];
  const float* trans_E = (const float*)d_in[2];
  const float* trans_S = (const float*)d_in[3];
  const int*   neg_idx = (const int*)d_in[4];

  // ws layout: [0,256): 2*B double accumulators (pos then neg), zeroed each call
  //            [256, 256 + ROWS*N*4): sorted S rows (67 MB)
  double* acc = (double*)d_ws;
  float*  Vs  = (float*)((char*)d_ws + 256);

  hipMemsetAsync(d_ws, 0, 256, stream);
  sort_rows<<<ROWS, NTH, 0, stream>>>(style_E, style_S, Vs);
  loss_rows<<<ROWS, NTH, 0, stream>>>(trans_E, trans_S, Vs, neg_idx, acc);
  finalize<<<1, 64, 0, stream>>>(acc, (float*)d_out);
}

// Round 2
// 240.212 us; speedup vs baseline: 3.7004x; 3.7004x over previous
//
#include <hip/hip_runtime.h>

// EFDM loss — reduced form:
//   pos_sum[b]  = sum over (a,p,c,j) of (sortT[a,p,b,c][j] - sortS[a,p,b,c][j])^2
//   neg_sum[b]  = sum over (a,p,k,c,j) of (sortT[a,p,b,c][j] - sortS[a,p,nb(b,k),c][j])^2
//   out = sum_b pos_sum[b]/neg_sum[b]          (the 1/(C*N) mean factors cancel)
//
// L=2, P=2, B=4, C=128, N=H*W=4096, K=2.  Rows = 2L*P*B*C = 4096.
// Register-resident bitonic sort: 16 elems/thread, 256 threads/row.
//   j<=8   : in-register (template-static indices)
//   j=16..512 : __shfl_xor within wave (lane-xor 1..32)
//   j=1024,2048 : LDS exchange (thread-xor 64,128), stride-17 pad (conflict-free)

constexpr int N    = 4096;
constexpr int NTH  = 256;
constexpr int CDIM = 128;
constexpr int BDIM = 4;
constexpr int KNEG = 2;
constexpr int ROWS = 4096;
constexpr int HALF = 2048;
constexpr int LPAD = 17;   // LDS row stride (floats) for exchange buffer

__device__ inline void cswap(float& a, float& b, bool up) {
  const float lo = fminf(a, b), hi = fmaxf(a, b);
  a = up ? lo : hi;
  b = up ? hi : lo;
}

// in-register pass, direction from local index m (stages k<=8)
template<int K, int J>
__device__ inline void reg_pass_local(float v[16]) {
  #pragma unroll
  for (int m = 0; m < 16; ++m)
    if ((m & J) == 0) cswap(v[m], v[m ^ J], (m & K) == 0);
}

// in-register pass, thread-uniform direction (stages k>=16)
template<int J>
__device__ inline void reg_pass_up(float v[16], bool up) {
  #pragma unroll
  for (int m = 0; m < 16; ++m)
    if ((m & J) == 0) cswap(v[m], v[m ^ J], up);
}

// one bitonic stage k=K (K>=16): cross-thread passes then register passes
template<int K>
__device__ inline void stage(float v[16], float* buf, int t) {
  const bool up = ((t & (K >> 4)) == 0);
  #pragma unroll
  for (int j = K >> 1; j >= 16; j >>= 1) {
    const int tmask = j >> 4;
    const bool keepmin = (up == ((t & tmask) == 0));
    if (tmask >= 64) {            // cross-wave: LDS exchange
      __syncthreads();            // protect prior reads of buf
      #pragma unroll
      for (int m = 0; m < 16; ++m) buf[t * LPAD + m] = v[m];
      __syncthreads();
      const int p = t ^ tmask;
      #pragma unroll
      for (int m = 0; m < 16; ++m) {
        const float o = buf[p * LPAD + m];
        v[m] = keepmin ? fminf(v[m], o) : fmaxf(v[m], o);
      }
    } else {                      // intra-wave: shuffle exchange
      #pragma unroll
      for (int m = 0; m < 16; ++m) {
        const float o = __shfl_xor(v[m], tmask, 64);
        v[m] = keepmin ? fminf(v[m], o) : fmaxf(v[m], o);
      }
    }
  }
  reg_pass_up<8>(v, up);
  reg_pass_up<4>(v, up);
  reg_pass_up<2>(v, up);
  reg_pass_up<1>(v, up);
}

// full ascending sort of 4096 floats: v[16] per thread, i = t*16+m
__device__ inline void sort4096(float v[16], float* buf, int t) {
  reg_pass_local<2, 1>(v);
  reg_pass_local<4, 2>(v); reg_pass_local<4, 1>(v);
  reg_pass_local<8, 4>(v); reg_pass_local<8, 2>(v); reg_pass_local<8, 1>(v);
  stage<16>(v, buf, t);   stage<32>(v, buf, t);   stage<64>(v, buf, t);
  stage<128>(v, buf, t);  stage<256>(v, buf, t);  stage<512>(v, buf, t);
  stage<1024>(v, buf, t); stage<2048>(v, buf, t); stage<4096>(v, buf, t);
}

__device__ inline void load16(const float* __restrict__ src, float v[16], int t) {
  const float4* s4 = (const float4*)src;
  #pragma unroll
  for (int q = 0; q < 4; ++q) {
    const float4 x = s4[t * 4 + q];
    v[q * 4 + 0] = x.x; v[q * 4 + 1] = x.y;
    v[q * 4 + 2] = x.z; v[q * 4 + 3] = x.w;
  }
}

__global__ __launch_bounds__(NTH)
void sort_rows(const float* __restrict__ a0, const float* __restrict__ a1,
               float* __restrict__ out) {
  __shared__ float buf[NTH * LPAD];
  const int t = threadIdx.x;
  const int r = blockIdx.x;
  const float* src = (r < HALF) ? a0 + (size_t)r * N
                                : a1 + (size_t)(r - HALF) * N;
  float v[16];
  load16(src, v, t);
  sort4096(v, buf, t);
  float4* d4 = (float4*)(out + (size_t)r * N);
  #pragma unroll
  for (int q = 0; q < 4; ++q)
    d4[t * 4 + q] = make_float4(v[q*4+0], v[q*4+1], v[q*4+2], v[q*4+3]);
}

__global__ __launch_bounds__(NTH)
void loss_rows(const float* __restrict__ t0, const float* __restrict__ t1,
               const float* __restrict__ Vs, const int* __restrict__ neg_idx,
               double* __restrict__ acc) {
  __shared__ float buf[NTH * LPAD];
  __shared__ float red[2][4];
  const int t = threadIdx.x;
  const int r = blockIdx.x;
  const float* src = (r < HALF) ? t0 + (size_t)r * N
                                : t1 + (size_t)(r - HALF) * N;
  float v[16];
  load16(src, v, t);
  sort4096(v, buf, t);

  // r = ((ap)*B + b)*C + c
  const int c  = r & (CDIM - 1);
  const int b  = (r / CDIM) & (BDIM - 1);
  const int ap = r / (CDIM * BDIM);

  float posp = 0.f, negp = 0.f;
  {
    const float4* vp4 = (const float4*)(Vs + (size_t)r * N);
    #pragma unroll
    for (int q = 0; q < 4; ++q) {
      const float4 x = vp4[t * 4 + q];
      float d0 = v[q*4+0] - x.x, d1 = v[q*4+1] - x.y;
      float d2 = v[q*4+2] - x.z, d3 = v[q*4+3] - x.w;
      posp += d0*d0 + d1*d1 + d2*d2 + d3*d3;
    }
  }
  #pragma unroll
  for (int k = 0; k < KNEG; ++k) {
    const int nb = neg_idx[b * KNEG + k];
    const float4* vn4 = (const float4*)(Vs + ((size_t)(ap * BDIM + nb) * CDIM + c) * N);
    #pragma unroll
    for (int q = 0; q < 4; ++q) {
      const float4 x = vn4[t * 4 + q];
      float d0 = v[q*4+0] - x.x, d1 = v[q*4+1] - x.y;
      float d2 = v[q*4+2] - x.z, d3 = v[q*4+3] - x.w;
      negp += d0*d0 + d1*d1 + d2*d2 + d3*d3;
    }
  }

  // wave64 shuffle reduce, then cross-wave via LDS
  #pragma unroll
  for (int off = 32; off > 0; off >>= 1) {
    posp += __shfl_down(posp, off, 64);
    negp += __shfl_down(negp, off, 64);
  }
  const int wid = t >> 6, lane = t & 63;
  if (lane == 0) { red[0][wid] = posp; red[1][wid] = negp; }
  __syncthreads();
  if (t == 0) {
    const float pt = red[0][0] + red[0][1] + red[0][2] + red[0][3];
    const float nt = red[1][0] + red[1][1] + red[1][2] + red[1][3];
    atomicAdd(&acc[b], (double)pt);
    atomicAdd(&acc[BDIM + b], (double)nt);
  }
}

__global__ void finalize(const double* __restrict__ acc, float* __restrict__ out) {
  if (threadIdx.x == 0 && blockIdx.x == 0) {
    double s = 0.0;
    for (int b = 0; b < BDIM; ++b) s += acc[b] / acc[BDIM + b];
    out[0] = (float)s;
  }
}

extern "C" void kernel_launch(void* const* d_in, const int* in_sizes, int n_in,
                              void* d_out, int out_size, void* d_ws, size_t ws_size,
                              hipStream_t stream) {
  const float* style_E = (const float*)d_in[0];
  const float* style_S = (const float*)d_in[1];
  const float* trans_E = (const float*)d_in[2];
  const float* trans_S = (const float*)d_in[3];
  const int*   neg_idx = (const int*)d_in[4];

  // ws layout: [0,256): 2*B double accumulators (pos then neg), zeroed each call
  //            [256, 256 + ROWS*N*4): sorted S rows (67 MB)
  double* acc = (double*)d_ws;
  float*  Vs  = (float*)((char*)d_ws + 256);

  hipMemsetAsync(d_ws, 0, 256, stream);
  sort_rows<<<ROWS, NTH, 0, stream>>>(style_E, style_S, Vs);
  loss_rows<<<ROWS, NTH, 0, stream>>>(trans_E, trans_S, Vs, neg_idx, acc);
  finalize<<<1, 64, 0, stream>>>(acc, (float*)d_out);
}

// Round 3
// 238.625 us; speedup vs baseline: 3.7250x; 1.0066x over previous
//
#include <hip/hip_runtime.h>

// EFDM loss — reduced form:
//   pos_sum[b]  = sum over (a,p,c,j) of (sortT[a,p,b,c][j] - sortS[a,p,b,c][j])^2
//   neg_sum[b]  = sum over (a,p,k,c,j) of (sortT[a,p,b,c][j] - sortS[a,p,nb(b,k),c][j])^2
//   out = sum_b pos_sum[b]/neg_sum[b]          (the 1/(C*N) mean factors cancel)
//
// Register bitonic sort, 16 elems/thread, 256 thr/row, with:
//  - sign-negation trick: descending threads sort -x ascending -> all compares static-min
//  - permlane16/32_swap paired butterfly for lane-xor 16/32 (VALU, no DS)
//  - DPP quad_perm for lane-xor 1/2; ds_swizzle for xor 4/8; LDS for thread-xor 64/128

constexpr int N    = 4096;
constexpr int NTH  = 256;
constexpr int CDIM = 128;
constexpr int BDIM = 4;
constexpr int KNEG = 2;
constexpr int ROWS = 4096;
constexpr int HALF = 2048;
constexpr int LPAD = 17;   // LDS row stride (floats), odd -> conflict-free b32

__device__ inline unsigned fasu(float x) { return __float_as_uint(x); }
__device__ inline float    usaf(unsigned x) { return __uint_as_float(x); }

__device__ inline void cswap_asc(float& a, float& b) {
  const float lo = fminf(a, b), hi = fmaxf(a, b);
  a = lo; b = hi;
}

// pre-stages k=2,4,8: direction static from local index m
template<int K, int J>
__device__ inline void local_pass(float v[16]) {
  #pragma unroll
  for (int m = 0; m < 16; ++m)
    if ((m & J) == 0) {
      if ((m & K) == 0) cswap_asc(v[m], v[m ^ J]);
      else              cswap_asc(v[m ^ J], v[m]);
    }
}

// ascending in-register tail: j = J, J/2, .., 1
template<int J>
__device__ inline void reg_passes_asc(float v[16]) {
  if constexpr (J >= 1) {
    #pragma unroll
    for (int m = 0; m < 16; ++m)
      if ((m & J) == 0) cswap_asc(v[m], v[m ^ J]);
    reg_passes_asc<(J >> 1)>(v);
  }
}

// DPP quad_perm exchange: 0xB1 = [1,0,3,2] = xor1, 0x4E = [2,3,0,1] = xor2
template<int CTRL>
__device__ inline float dpp_x(float x) {
  const int s = (int)fasu(x);
  return usaf((unsigned)__builtin_amdgcn_update_dpp(s, s, CTRL, 0xF, 0xF, false));
}

// lane-xor TM in {1,2,4,8}: per-lane keep-min = ((t&TM)==0)
template<int TM>
__device__ inline void pass_small(float v[16], int t) {
  const bool km = ((t & TM) == 0);
  #pragma unroll
  for (int m = 0; m < 16; ++m) {
    float o;
    if constexpr (TM == 1)      o = dpp_x<0xB1>(v[m]);
    else if constexpr (TM == 2) o = dpp_x<0x4E>(v[m]);
    else if constexpr (TM == 4)
      o = usaf((unsigned)__builtin_amdgcn_ds_swizzle((int)fasu(v[m]), 0x101F));
    else
      o = usaf((unsigned)__builtin_amdgcn_ds_swizzle((int)fasu(v[m]), 0x201F));
    v[m] = km ? fminf(v[m], o) : fmaxf(v[m], o);
  }
}

// gfx950 permlane swaps: both operands are read AND written.
// permlane32_swap: a' = {a[0:31], b[0:31]}, b' = {a[32:63], b[32:63]}
// permlane16_swap: a' = {a.r0, b.r0, a.r2, b.r2}, b' = {a.r1, b.r1, a.r3, b.r3}
__device__ inline void swap32(float& a, float& b) {
  asm("v_permlane32_swap_b32 %0, %1" : "+v"(a), "+v"(b));
}
__device__ inline void swap16(float& a, float& b) {
  asm("v_permlane16_swap_b32 %0, %1" : "+v"(a), "+v"(b));
}

// lane-xor 16/32 butterfly on an element PAIR: 2 swaps + min + max gives both
// results with min landing in the (t&TM)==0 lanes — exactly keep-min there.
template<bool IS32>
__device__ inline void pass_perm(float v[16]) {
  #pragma unroll
  for (int m = 0; m < 16; m += 2) {
    float a = v[m], b = v[m + 1];
    if constexpr (IS32) swap32(a, b); else swap16(a, b);
    float mn = fminf(a, b);
    float mx = fmaxf(a, b);
    if constexpr (IS32) swap32(mn, mx); else swap16(mn, mx);
    v[m] = mn; v[m + 1] = mx;
  }
}

// thread-xor 64/128 via LDS; keep decision wave-uniform -> pure min or max
template<int TM>
__device__ inline void pass_lds(float v[16], float* buf, int t) {
  __syncthreads();
  #pragma unroll
  for (int m = 0; m < 16; ++m) buf[t * LPAD + m] = v[m];
  __syncthreads();
  const int p = t ^ TM;
  if ((t & TM) == 0) {
    #pragma unroll
    for (int m = 0; m < 16; ++m) v[m] = fminf(v[m], buf[p * LPAD + m]);
  } else {
    #pragma unroll
    for (int m = 0; m < 16; ++m) v[m] = fmaxf(v[m], buf[p * LPAD + m]);
  }
}

template<int K, int J>
__device__ inline void cross_passes(float v[16], float* buf, int t) {
  if constexpr (J >= 16) {
    constexpr int TM = J >> 4;
    if constexpr (TM >= 64)      pass_lds<TM>(v, buf, t);
    else if constexpr (TM == 32) pass_perm<true>(v);
    else if constexpr (TM == 16) pass_perm<false>(v);
    else                         pass_small<TM>(v, t);
    cross_passes<K, (J >> 1)>(v, buf, t);
  }
}

__device__ inline void apply_flip(float v[16], unsigned f) {
  #pragma unroll
  for (int m = 0; m < 16; ++m) v[m] = usaf(fasu(v[m]) ^ f);
}

// one bitonic stage of width K (>=16), operating in sign-flipped space
template<int K>
__device__ inline void stage_n(float v[16], float* buf, int t, unsigned& cur) {
  const unsigned f = (t & (K >> 4)) ? 0x80000000u : 0u;
  apply_flip(v, f ^ cur);
  cur = f;
  cross_passes<K, (K >> 1)>(v, buf, t);
  reg_passes_asc<8>(v);
}

// full ascending sort of 4096 floats: v[16] per thread, i = t*16+m
__device__ inline void sort4096(float v[16], float* buf, int t) {
  local_pass<2, 1>(v);
  local_pass<4, 2>(v); local_pass<4, 1>(v);
  local_pass<8, 4>(v); local_pass<8, 2>(v); local_pass<8, 1>(v);
  unsigned cur = 0;
  stage_n<16>(v, buf, t, cur);
  stage_n<32>(v, buf, t, cur);
  stage_n<64>(v, buf, t, cur);
  stage_n<128>(v, buf, t, cur);
  stage_n<256>(v, buf, t, cur);
  stage_n<512>(v, buf, t, cur);
  stage_n<1024>(v, buf, t, cur);
  stage_n<2048>(v, buf, t, cur);
  stage_n<4096>(v, buf, t, cur);
  apply_flip(v, cur);   // cur == 0 for all t<256, but keep it general
}

__device__ inline void load16(const float* __restrict__ src, float v[16], int t) {
  const float4* s4 = (const float4*)src;
  #pragma unroll
  for (int q = 0; q < 4; ++q) {
    const float4 x = s4[t * 4 + q];
    v[q * 4 + 0] = x.x; v[q * 4 + 1] = x.y;
    v[q * 4 + 2] = x.z; v[q * 4 + 3] = x.w;
  }
}

__global__ __launch_bounds__(NTH)
void sort_rows(const float* __restrict__ a0, const float* __restrict__ a1,
               float* __restrict__ out) {
  __shared__ float buf[NTH * LPAD];
  const int t = threadIdx.x;
  const int r = blockIdx.x;
  const float* src = (r < HALF) ? a0 + (size_t)r * N
                                : a1 + (size_t)(r - HALF) * N;
  float v[16];
  load16(src, v, t);
  sort4096(v, buf, t);
  float4* d4 = (float4*)(out + (size_t)r * N);
  #pragma unroll
  for (int q = 0; q < 4; ++q)
    d4[t * 4 + q] = make_float4(v[q*4+0], v[q*4+1], v[q*4+2], v[q*4+3]);
}

__global__ __launch_bounds__(NTH)
void loss_rows(const float* __restrict__ t0, const float* __restrict__ t1,
               const float* __restrict__ Vs, const int* __restrict__ neg_idx,
               double* __restrict__ acc) {
  __shared__ float buf[NTH * LPAD];
  __shared__ float red[2][4];
  const int t = threadIdx.x;
  const int r = blockIdx.x;
  const float* src = (r < HALF) ? t0 + (size_t)r * N
                                : t1 + (size_t)(r - HALF) * N;
  float v[16];
  load16(src, v, t);
  sort4096(v, buf, t);

  // r = ((ap)*B + b)*C + c
  const int c  = r & (CDIM - 1);
  const int b  = (r / CDIM) & (BDIM - 1);
  const int ap = r / (CDIM * BDIM);

  float posp = 0.f, negp = 0.f;
  {
    const float4* vp4 = (const float4*)(Vs + (size_t)r * N);
    #pragma unroll
    for (int q = 0; q < 4; ++q) {
      const float4 x = vp4[t * 4 + q];
      float d0 = v[q*4+0] - x.x, d1 = v[q*4+1] - x.y;
      float d2 = v[q*4+2] - x.z, d3 = v[q*4+3] - x.w;
      posp += d0*d0 + d1*d1 + d2*d2 + d3*d3;
    }
  }
  #pragma unroll
  for (int k = 0; k < KNEG; ++k) {
    const int nb = neg_idx[b * KNEG + k];
    const float4* vn4 = (const float4*)(Vs + ((size_t)(ap * BDIM + nb) * CDIM + c) * N);
    #pragma unroll
    for (int q = 0; q < 4; ++q) {
      const float4 x = vn4[t * 4 + q];
      float d0 = v[q*4+0] - x.x, d1 = v[q*4+1] - x.y;
      float d2 = v[q*4+2] - x.z, d3 = v[q*4+3] - x.w;
      negp += d0*d0 + d1*d1 + d2*d2 + d3*d3;
    }
  }

  #pragma unroll
  for (int off = 32; off > 0; off >>= 1) {
    posp += __shfl_down(posp, off, 64);
    negp += __shfl_down(negp, off, 64);
  }
  const int wid = t >> 6, lane = t & 63;
  if (lane == 0) { red[0][wid] = posp; red[1][wid] = negp; }
  __syncthreads();
  if (t == 0) {
    const float pt = red[0][0] + red[0][1] + red[0][2] + red[0][3];
    const float nt = red[1][0] + red[1][1] + red[1][2] + red[1][3];
    atomicAdd(&acc[b], (double)pt);
    atomicAdd(&acc[BDIM + b], (double)nt);
  }
}

__global__ void finalize(const double* __restrict__ acc, float* __restrict__ out) {
  if (threadIdx.x == 0 && blockIdx.x == 0) {
    double s = 0.0;
    for (int b = 0; b < BDIM; ++b) s += acc[b] / acc[BDIM + b];
    out[0] = (float)s;
  }
}

extern "C" void kernel_launch(void* const* d_in, const int* in_sizes, int n_in,
                              void* d_out, int out_size, void* d_ws, size_t ws_size,
                              hipStream_t stream) {
  const float* style_E = (const float*)d_in[0];
  const float* style_S = (const float*)d_in[1];
  const float* trans_E = (const float*)d_in[2];
  const float* trans_S = (const float*)d_in[3];
  const int*   neg_idx = (const int*)d_in[4];

  double* acc = (double*)d_ws;
  float*  Vs  = (float*)((char*)d_ws + 256);

  hipMemsetAsync(d_ws, 0, 256, stream);
  sort_rows<<<ROWS, NTH, 0, stream>>>(style_E, style_S, Vs);
  loss_rows<<<ROWS, NTH, 0, stream>>>(trans_E, trans_S, Vs, neg_idx, acc);
  finalize<<<1, 64, 0, stream>>>(acc, (float*)d_out);
}